// Round 1
// baseline (388.738 us; speedup 1.0000x reference)
//
#include <hip/hip_runtime.h>

#define N_USERS 100000
#define EMBED   128

// ---------------------------------------------------------------- copy layer0
__global__ __launch_bounds__(256) void copy_kernel(const float4* __restrict__ src,
                                                   float4* __restrict__ dst, int n4) {
  int i = blockIdx.x * blockDim.x + threadIdx.x;
  if (i < n4) dst[i] = src[i];
}

// ---------------------------------------------------------------- row pointers
// row_ptr[r] = lower_bound(rows, r); rows is sorted ascending.
__global__ __launch_bounds__(256) void rowptr_kernel(const int* __restrict__ rows,
                                                     int* __restrict__ row_ptr,
                                                     int n_rows, int n_edges) {
  int r = blockIdx.x * blockDim.x + threadIdx.x;
  if (r > n_rows) return;
  int lo = 0, hi = n_edges;
  while (lo < hi) {
    int mid = (lo + hi) >> 1;
    if (rows[mid] < r) lo = mid + 1; else hi = mid;
  }
  row_ptr[r] = lo;
}

// ---------------------------------------------------------------- dense GEMM
// Y = X @ W   (X: [n,128], W: [128,128] row-major, Y: [n,128])
// 256 threads: 32 rows x 128 cols per block; each thread 4 rows x 4 cols.
__global__ __launch_bounds__(256) void gemm_kernel(const float* __restrict__ X,
                                                   const float* __restrict__ W,
                                                   float* __restrict__ Y) {
  __shared__ float Ws[64 * 128];   // one K-half of W (32 KB)
  __shared__ float Xs[128][33];    // transposed X tile, padded (16.9 KB)
  const int tid = threadIdx.x;
  const int jg  = tid & 31;        // column group (j0 = jg*4)
  const int rg  = tid >> 5;        // row group    (r0 = rg*4)
  const int j0  = jg * 4;
  const int r0  = rg * 4;
  const int row0 = blockIdx.x * 32;

  // stage X tile transposed: Xs[k][r] = X[row0+r][k]
  const float4* X4 = (const float4*)(X + (size_t)row0 * EMBED);
  #pragma unroll
  for (int i = 0; i < 4; ++i) {
    int c  = tid + 256 * i;        // chunk 0..1023
    int rc = c >> 5;               // row in tile 0..31
    int kc = c & 31;               // float4 index in row
    float4 v = X4[rc * 32 + kc];
    Xs[kc * 4 + 0][rc] = v.x;
    Xs[kc * 4 + 1][rc] = v.y;
    Xs[kc * 4 + 2][rc] = v.z;
    Xs[kc * 4 + 3][rc] = v.w;
  }

  float acc[4][4];
  #pragma unroll
  for (int i = 0; i < 4; ++i)
    #pragma unroll
    for (int j = 0; j < 4; ++j) acc[i][j] = 0.f;

  const float4* W4  = (const float4*)W;
  float4*       Ws4 = (float4*)Ws;

  for (int kh = 0; kh < 2; ++kh) {
    __syncthreads();
    // stage W rows [kh*64, kh*64+64): 2048 float4
    #pragma unroll
    for (int i = 0; i < 8; ++i) {
      int idx = tid + 256 * i;
      Ws4[idx] = W4[kh * 2048 + idx];
    }
    __syncthreads();
    #pragma unroll 4
    for (int k = 0; k < 64; ++k) {
      float4 wv = Ws4[k * 32 + jg];
      float wr[4] = {wv.x, wv.y, wv.z, wv.w};
      float xv[4];
      #pragma unroll
      for (int i = 0; i < 4; ++i) xv[i] = Xs[kh * 64 + k][r0 + i];
      #pragma unroll
      for (int i = 0; i < 4; ++i)
        #pragma unroll
        for (int j = 0; j < 4; ++j)
          acc[i][j] = fmaf(xv[i], wr[j], acc[i][j]);
    }
  }

  #pragma unroll
  for (int i = 0; i < 4; ++i) {
    float4 o = {acc[i][0], acc[i][1], acc[i][2], acc[i][3]};
    *(float4*)(&Y[(size_t)(row0 + r0 + i) * EMBED + j0]) = o;
  }
}

// ---------------------------------------------------------------- SpMM + residual
// OUT[r] = X[r] + sum_e vals[e] * XT[cols[e]]  over edges of row r.
// 32 lanes per row (float4 each), 8 rows per 256-thread block.
__global__ __launch_bounds__(256) void spmm_kernel(const float* __restrict__ XT,
                                                   const float* __restrict__ X,
                                                   const int* __restrict__ row_ptr,
                                                   const int* __restrict__ cols,
                                                   const float* __restrict__ vals,
                                                   float* __restrict__ OUT) {
  const int tid  = threadIdx.x;
  const int lane = tid & 31;
  const int rg   = tid >> 5;
  const int row  = blockIdx.x * 8 + rg;
  if (row >= N_USERS) return;
  const int start = row_ptr[row];
  const int end   = row_ptr[row + 1];
  const float4* XT4 = (const float4*)XT;
  float4 acc = ((const float4*)X)[(size_t)row * 32 + lane];
  for (int e = start; e < end; ++e) {
    const int   c = cols[e];
    const float v = vals[e];
    float4 xv = XT4[(size_t)c * 32 + lane];
    acc.x = fmaf(v, xv.x, acc.x);
    acc.y = fmaf(v, xv.y, acc.y);
    acc.z = fmaf(v, xv.z, acc.z);
    acc.w = fmaf(v, xv.w, acc.w);
  }
  ((float4*)OUT)[(size_t)row * 32 + lane] = acc;
}

// ---------------------------------------------------------------- launch
extern "C" void kernel_launch(void* const* d_in, const int* in_sizes, int n_in,
                              void* d_out, int out_size, void* d_ws, size_t ws_size,
                              hipStream_t stream) {
  const float* user_embeds = (const float*)d_in[0];
  const int*   s_rows      = (const int*)d_in[1];
  const int*   s_cols      = (const int*)d_in[2];
  const float* s_values    = (const float*)d_in[3];
  const float* W0          = (const float*)d_in[4];
  const float* W1          = (const float*)d_in[5];
  float* out = (float*)d_out;

  const int n_edges = in_sizes[1];
  const size_t layer = (size_t)N_USERS * EMBED;

  float* xt      = (float*)d_ws;                                   // 51.2 MB
  int*   row_ptr = (int*)((char*)d_ws + layer * sizeof(float));    // 400 KB

  // layer 0 = input embeddings
  {
    int n4 = (int)(layer / 4);
    copy_kernel<<<(n4 + 255) / 256, 256, 0, stream>>>(
        (const float4*)user_embeds, (float4*)out, n4);
  }
  // CSR row pointers (shared by both layers)
  rowptr_kernel<<<(N_USERS + 1 + 255) / 256, 256, 0, stream>>>(
      s_rows, row_ptr, N_USERS, n_edges);

  const float* Wl[2] = {W0, W1};
  for (int l = 0; l < 2; ++l) {
    gemm_kernel<<<N_USERS / 32, 256, 0, stream>>>(out + l * layer, Wl[l], xt);
    spmm_kernel<<<N_USERS / 8, 256, 0, stream>>>(xt, out + l * layer, row_ptr,
                                                 s_cols, s_values,
                                                 out + (l + 1) * layer);
  }
}

// Round 2
// 262.616 us; speedup vs baseline: 1.4802x; 1.4802x over previous
//
#include <hip/hip_runtime.h>

#define N_USERS 100000
#define EMBED   128

typedef __attribute__((ext_vector_type(8))) short bf16x8;
typedef __attribute__((ext_vector_type(4))) float f32x4;

// ---------------------------------------------------------------- copy layer0
__global__ __launch_bounds__(256) void copy_kernel(const float4* __restrict__ src,
                                                   float4* __restrict__ dst, int n4) {
  int i = blockIdx.x * blockDim.x + threadIdx.x;
  if (i < n4) dst[i] = src[i];
}

// ---------------------------------------------------------------- row pointers
__global__ __launch_bounds__(256) void rowptr_kernel(const int* __restrict__ rows,
                                                     int* __restrict__ row_ptr,
                                                     int n_rows, int n_edges) {
  int r = blockIdx.x * blockDim.x + threadIdx.x;
  if (r > n_rows) return;
  int lo = 0, hi = n_edges;
  while (lo < hi) {
    int mid = (lo + hi) >> 1;
    if (rows[mid] < r) lo = mid + 1; else hi = mid;
  }
  row_ptr[r] = lo;
}

// ---------------------------------------------------------------- W -> Wt bf16
// Wt[n][k] = bf16(W[k][n]); stored as 64 uint per row (pairs of bf16 along k).
__global__ __launch_bounds__(256) void wconv_kernel(const float* __restrict__ W0,
                                                    const float* __restrict__ W1,
                                                    uint* __restrict__ Wt0,
                                                    uint* __restrict__ Wt1) {
  const float* W  = blockIdx.x ? W1 : W0;
  uint*        Wt = blockIdx.x ? Wt1 : Wt0;
  for (int idx = threadIdx.x; idx < 128 * 64; idx += 256) {
    int n = idx >> 6;          // 0..127
    int kp = idx & 63;         // k pair
    float a = W[(2 * kp) * 128 + n];
    float b = W[(2 * kp + 1) * 128 + n];
    uint o;
    asm("v_cvt_pk_bf16_f32 %0, %1, %2" : "=v"(o) : "v"(a), "v"(b));
    Wt[n * 64 + kp] = o;
  }
}

// ---------------------------------------------------------------- MFMA GEMM
// Computes Y(bf16)[m][n] = (X @ W)[m][n] via G = W^T * X^T tiles:
//   A = Wt panel (A[n][k] = W[k][n]), B = X^T (B[k][m] = X[m][k])
//   D: col = lane&15 -> m (user), row = 4*(lane>>4)+reg -> n.
// 256 threads = 4 waves, wave handles 16 users x 128 cols. No LDS.
__global__ __launch_bounds__(256) void gemm_kernel(const float* __restrict__ X,
                                                   const ushort* __restrict__ Wt,
                                                   ushort* __restrict__ Y) {
  const int tid  = threadIdx.x;
  const int wave = tid >> 6;
  const int lane = tid & 63;
  const int l15  = lane & 15;
  const int lg   = lane >> 4;                       // 0..3 (k-chunk)
  const int m    = blockIdx.x * 64 + wave * 16 + l15;
  const int mc   = m < N_USERS ? m : N_USERS - 1;
  const float* xrow = X + (size_t)mc * EMBED;

  f32x4 acc[8];
  #pragma unroll
  for (int t = 0; t < 8; ++t) acc[t] = (f32x4){0.f, 0.f, 0.f, 0.f};

  #pragma unroll
  for (int s = 0; s < 4; ++s) {
    const int k0 = s * 32 + lg * 8;
    float4 xa = *(const float4*)(xrow + k0);
    float4 xb = *(const float4*)(xrow + k0 + 4);
    union { bf16x8 v; uint u[4]; } bfr;
    asm("v_cvt_pk_bf16_f32 %0, %1, %2" : "=v"(bfr.u[0]) : "v"(xa.x), "v"(xa.y));
    asm("v_cvt_pk_bf16_f32 %0, %1, %2" : "=v"(bfr.u[1]) : "v"(xa.z), "v"(xa.w));
    asm("v_cvt_pk_bf16_f32 %0, %1, %2" : "=v"(bfr.u[2]) : "v"(xb.x), "v"(xb.y));
    asm("v_cvt_pk_bf16_f32 %0, %1, %2" : "=v"(bfr.u[3]) : "v"(xb.z), "v"(xb.w));
    #pragma unroll
    for (int nt = 0; nt < 8; ++nt) {
      union { bf16x8 v; uint4 u; } afr;
      afr.u = *(const uint4*)(Wt + (size_t)(nt * 16 + l15) * 128 + k0);
      acc[nt] = __builtin_amdgcn_mfma_f32_16x16x32_bf16(afr.v, bfr.v, acc[nt], 0, 0, 0);
    }
  }

  if (m < N_USERS) {
    ushort* yrow = Y + (size_t)m * EMBED;
    #pragma unroll
    for (int nt = 0; nt < 8; ++nt) {
      uint2 o;
      asm("v_cvt_pk_bf16_f32 %0, %1, %2" : "=v"(o.x) : "v"(acc[nt][0]), "v"(acc[nt][1]));
      asm("v_cvt_pk_bf16_f32 %0, %1, %2" : "=v"(o.y) : "v"(acc[nt][2]), "v"(acc[nt][3]));
      *(uint2*)(yrow + nt * 16 + lg * 4) = o;
    }
  }
}

// ---------------------------------------------------------------- SpMM + residual
// OUT[r] = X[r] + sum_e vals[e] * bf16(XT[cols[e]]); 32 lanes/row (4 cols each).
__global__ __launch_bounds__(256) void spmm_kernel(const ushort* __restrict__ XT,
                                                   const float* __restrict__ X,
                                                   const int* __restrict__ row_ptr,
                                                   const int* __restrict__ cols,
                                                   const float* __restrict__ vals,
                                                   float* __restrict__ OUT) {
  const int tid  = threadIdx.x;
  const int lane = tid & 31;
  const int rg   = tid >> 5;
  const int row  = blockIdx.x * 8 + rg;
  if (row >= N_USERS) return;
  const int start = row_ptr[row];
  const int end   = row_ptr[row + 1];
  const uint2* XT2 = (const uint2*)XT;
  float4 acc = ((const float4*)X)[(size_t)row * 32 + lane];

  int e = start;
  for (; e + 2 <= end; e += 2) {
    int   c0 = cols[e],     c1 = cols[e + 1];
    float v0 = vals[e],     v1 = vals[e + 1];
    uint2 u0 = XT2[(size_t)c0 * 32 + lane];
    uint2 u1 = XT2[(size_t)c1 * 32 + lane];
    acc.x = fmaf(v0, __uint_as_float(u0.x << 16),          acc.x);
    acc.y = fmaf(v0, __uint_as_float(u0.x & 0xffff0000u),  acc.y);
    acc.z = fmaf(v0, __uint_as_float(u0.y << 16),          acc.z);
    acc.w = fmaf(v0, __uint_as_float(u0.y & 0xffff0000u),  acc.w);
    acc.x = fmaf(v1, __uint_as_float(u1.x << 16),          acc.x);
    acc.y = fmaf(v1, __uint_as_float(u1.x & 0xffff0000u),  acc.y);
    acc.z = fmaf(v1, __uint_as_float(u1.y << 16),          acc.z);
    acc.w = fmaf(v1, __uint_as_float(u1.y & 0xffff0000u),  acc.w);
  }
  if (e < end) {
    int   c0 = cols[e];
    float v0 = vals[e];
    uint2 u0 = XT2[(size_t)c0 * 32 + lane];
    acc.x = fmaf(v0, __uint_as_float(u0.x << 16),          acc.x);
    acc.y = fmaf(v0, __uint_as_float(u0.x & 0xffff0000u),  acc.y);
    acc.z = fmaf(v0, __uint_as_float(u0.y << 16),          acc.z);
    acc.w = fmaf(v0, __uint_as_float(u0.y & 0xffff0000u),  acc.w);
  }
  ((float4*)OUT)[(size_t)row * 32 + lane] = acc;
}

// ---------------------------------------------------------------- launch
extern "C" void kernel_launch(void* const* d_in, const int* in_sizes, int n_in,
                              void* d_out, int out_size, void* d_ws, size_t ws_size,
                              hipStream_t stream) {
  const float* user_embeds = (const float*)d_in[0];
  const int*   s_rows      = (const int*)d_in[1];
  const int*   s_cols      = (const int*)d_in[2];
  const float* s_values    = (const float*)d_in[3];
  const float* W0          = (const float*)d_in[4];
  const float* W1          = (const float*)d_in[5];
  float* out = (float*)d_out;

  const int n_edges = in_sizes[1];
  const size_t layer = (size_t)N_USERS * EMBED;

  char* ws = (char*)d_ws;
  ushort* xt      = (ushort*)ws;                       ws += layer * sizeof(ushort); // 25.6 MB
  ushort* Wt0     = (ushort*)ws;                       ws += 128 * 128 * sizeof(ushort);
  ushort* Wt1     = (ushort*)ws;                       ws += 128 * 128 * sizeof(ushort);
  int*    row_ptr = (int*)ws;

  {
    int n4 = (int)(layer / 4);
    copy_kernel<<<(n4 + 255) / 256, 256, 0, stream>>>(
        (const float4*)user_embeds, (float4*)out, n4);
  }
  rowptr_kernel<<<(N_USERS + 1 + 255) / 256, 256, 0, stream>>>(
      s_rows, row_ptr, N_USERS, n_edges);
  wconv_kernel<<<2, 256, 0, stream>>>(W0, W1, (uint*)Wt0, (uint*)Wt1);

  const ushort* Wtl[2] = {Wt0, Wt1};
  for (int l = 0; l < 2; ++l) {
    gemm_kernel<<<(N_USERS + 63) / 64, 256, 0, stream>>>(out + l * layer, Wtl[l], xt);
    spmm_kernel<<<(N_USERS + 7) / 8, 256, 0, stream>>>(xt, out + l * layer, row_ptr,
                                                       s_cols, s_values,
                                                       out + (l + 1) * layer);
  }
}

// Round 4
// 239.504 us; speedup vs baseline: 1.6231x; 1.0965x over previous
//
#include <hip/hip_runtime.h>

#define N_USERS 100000
#define EMBED   128

typedef __attribute__((ext_vector_type(8))) short bf16x8;
typedef __attribute__((ext_vector_type(4))) float f32x4;

// ---------------------------------------------------------------- row pointers
__global__ __launch_bounds__(256) void rowptr_kernel(const int* __restrict__ rows,
                                                     int* __restrict__ row_ptr,
                                                     int n_rows, int n_edges) {
  int r = blockIdx.x * blockDim.x + threadIdx.x;
  if (r > n_rows) return;
  int lo = 0, hi = n_edges;
  while (lo < hi) {
    int mid = (lo + hi) >> 1;
    if (rows[mid] < r) lo = mid + 1; else hi = mid;
  }
  row_ptr[r] = lo;
}

// ---------------------------------------------------------------- W -> Wt bf16
// Wt[n][k] = bf16(W[k][n]); stored as 64 uint per row (pairs of bf16 along k).
__global__ __launch_bounds__(256) void wconv_kernel(const float* __restrict__ W0,
                                                    const float* __restrict__ W1,
                                                    uint* __restrict__ Wt0,
                                                    uint* __restrict__ Wt1) {
  const float* W  = blockIdx.x ? W1 : W0;
  uint*        Wt = blockIdx.x ? Wt1 : Wt0;
  for (int idx = threadIdx.x; idx < 128 * 64; idx += 256) {
    int n = idx >> 6;
    int kp = idx & 63;
    float a = W[(2 * kp) * 128 + n];
    float b = W[(2 * kp + 1) * 128 + n];
    uint o;
    asm("v_cvt_pk_bf16_f32 %0, %1, %2" : "=v"(o) : "v"(a), "v"(b));
    Wt[n * 64 + kp] = o;
  }
}

// ---------------------------------------------------------------- MFMA GEMM
// Y(bf16)[m][n] = (X @ W)[m][n]; optionally streams X through to Xcopy (f32).
__global__ __launch_bounds__(256) void gemm_kernel(const float* __restrict__ X,
                                                   const ushort* __restrict__ Wt,
                                                   ushort* __restrict__ Y,
                                                   float* __restrict__ Xcopy) {
  const int tid  = threadIdx.x;
  const int wave = tid >> 6;
  const int lane = tid & 63;
  const int l15  = lane & 15;
  const int lg   = lane >> 4;                       // 0..3 (k-chunk)
  const int m    = blockIdx.x * 64 + wave * 16 + l15;
  const int mc   = m < N_USERS ? m : N_USERS - 1;
  const bool act = m < N_USERS;
  const float* xrow = X + (size_t)mc * EMBED;

  f32x4 acc[8];
  #pragma unroll
  for (int t = 0; t < 8; ++t) acc[t] = (f32x4){0.f, 0.f, 0.f, 0.f};

  #pragma unroll
  for (int s = 0; s < 4; ++s) {
    const int k0 = s * 32 + lg * 8;
    float4 xa = *(const float4*)(xrow + k0);
    float4 xb = *(const float4*)(xrow + k0 + 4);
    if (Xcopy && act) {
      *(float4*)(Xcopy + (size_t)m * EMBED + k0)     = xa;
      *(float4*)(Xcopy + (size_t)m * EMBED + k0 + 4) = xb;
    }
    union { bf16x8 v; uint u[4]; } bfr;
    asm("v_cvt_pk_bf16_f32 %0, %1, %2" : "=v"(bfr.u[0]) : "v"(xa.x), "v"(xa.y));
    asm("v_cvt_pk_bf16_f32 %0, %1, %2" : "=v"(bfr.u[1]) : "v"(xa.z), "v"(xa.w));
    asm("v_cvt_pk_bf16_f32 %0, %1, %2" : "=v"(bfr.u[2]) : "v"(xb.x), "v"(xb.y));
    asm("v_cvt_pk_bf16_f32 %0, %1, %2" : "=v"(bfr.u[3]) : "v"(xb.z), "v"(xb.w));
    #pragma unroll
    for (int nt = 0; nt < 8; ++nt) {
      union { bf16x8 v; uint4 u; } afr;
      afr.u = *(const uint4*)(Wt + (size_t)(nt * 16 + l15) * 128 + k0);
      acc[nt] = __builtin_amdgcn_mfma_f32_16x16x32_bf16(afr.v, bfr.v, acc[nt], 0, 0, 0);
    }
  }

  if (act) {
    ushort* yrow = Y + (size_t)m * EMBED;
    #pragma unroll
    for (int nt = 0; nt < 8; ++nt) {
      uint2 o;
      asm("v_cvt_pk_bf16_f32 %0, %1, %2" : "=v"(o.x) : "v"(acc[nt][0]), "v"(acc[nt][1]));
      asm("v_cvt_pk_bf16_f32 %0, %1, %2" : "=v"(o.y) : "v"(acc[nt][2]), "v"(acc[nt][3]));
      *(uint2*)(yrow + nt * 16 + lg * 4) = o;
    }
  }
}

// ---------------------------------------------------------------- SpMM + residual
// OUT[r] = X[r] + sum_e vals[e] * bf16(XT[cols[e]])
// 16 lanes per row (8 cols / 16B gather each), 16 rows per 256-thread block.
#define FMA8(g, v)                                                     \
  do {                                                                 \
    acc[0] = fmaf((v), __uint_as_float((g).x << 16),         acc[0]);  \
    acc[1] = fmaf((v), __uint_as_float((g).x & 0xffff0000u), acc[1]);  \
    acc[2] = fmaf((v), __uint_as_float((g).y << 16),         acc[2]);  \
    acc[3] = fmaf((v), __uint_as_float((g).y & 0xffff0000u), acc[3]);  \
    acc[4] = fmaf((v), __uint_as_float((g).z << 16),         acc[4]);  \
    acc[5] = fmaf((v), __uint_as_float((g).z & 0xffff0000u), acc[5]);  \
    acc[6] = fmaf((v), __uint_as_float((g).w << 16),         acc[6]);  \
    acc[7] = fmaf((v), __uint_as_float((g).w & 0xffff0000u), acc[7]);  \
  } while (0)

__global__ __launch_bounds__(256) void spmm_kernel(const ushort* __restrict__ XT,
                                                   const float* __restrict__ X,
                                                   const int* __restrict__ row_ptr,
                                                   const int* __restrict__ cols,
                                                   const float* __restrict__ vals,
                                                   float* __restrict__ OUT) {
  const int tid = threadIdx.x;
  const int l   = tid & 15;        // lane within row group (8 cols each)
  const int rg  = tid >> 4;        // 0..15
  const int row = blockIdx.x * 16 + rg;
  if (row >= N_USERS) return;
  const int start = row_ptr[row];
  const int end   = row_ptr[row + 1];
  const uint4* XT4 = (const uint4*)XT;   // row stride = 16 uint4

  float acc[8];
  {
    float4 r0 = *(const float4*)(X + (size_t)row * EMBED + l * 8);
    float4 r1 = *(const float4*)(X + (size_t)row * EMBED + l * 8 + 4);
    acc[0] = r0.x; acc[1] = r0.y; acc[2] = r0.z; acc[3] = r0.w;
    acc[4] = r1.x; acc[5] = r1.y; acc[6] = r1.z; acc[7] = r1.w;
  }

  int e = start;
  // peel to 4-alignment so int4/float4 metadata loads are aligned
  int e_pre = (start + 3) & ~3;
  if (e_pre > end) e_pre = end;
  for (; e < e_pre; ++e) {
    int   c = cols[e];
    float v = vals[e];
    uint4 g = XT4[(size_t)c * 16 + l];
    FMA8(g, v);
  }
  for (; e + 4 <= end; e += 4) {
    int4   c = *(const int4*)(cols + e);
    float4 v = *(const float4*)(vals + e);
    uint4 g0 = XT4[(size_t)c.x * 16 + l];
    uint4 g1 = XT4[(size_t)c.y * 16 + l];
    uint4 g2 = XT4[(size_t)c.z * 16 + l];
    uint4 g3 = XT4[(size_t)c.w * 16 + l];
    FMA8(g0, v.x);
    FMA8(g1, v.y);
    FMA8(g2, v.z);
    FMA8(g3, v.w);
  }
  for (; e < end; ++e) {
    int   c = cols[e];
    float v = vals[e];
    uint4 g = XT4[(size_t)c * 16 + l];
    FMA8(g, v);
  }

  float4 o0 = {acc[0], acc[1], acc[2], acc[3]};
  float4 o1 = {acc[4], acc[5], acc[6], acc[7]};
  *(float4*)(OUT + (size_t)row * EMBED + l * 8)     = o0;
  *(float4*)(OUT + (size_t)row * EMBED + l * 8 + 4) = o1;
}

// ---------------------------------------------------------------- launch
extern "C" void kernel_launch(void* const* d_in, const int* in_sizes, int n_in,
                              void* d_out, int out_size, void* d_ws, size_t ws_size,
                              hipStream_t stream) {
  const float* user_embeds = (const float*)d_in[0];
  const int*   s_rows      = (const int*)d_in[1];
  const int*   s_cols      = (const int*)d_in[2];
  const float* s_values    = (const float*)d_in[3];
  const float* W0          = (const float*)d_in[4];
  const float* W1          = (const float*)d_in[5];
  float* out = (float*)d_out;

  const int n_edges = in_sizes[1];
  const size_t layer = (size_t)N_USERS * EMBED;

  char* ws = (char*)d_ws;
  ushort* xt      = (ushort*)ws;   ws += layer * sizeof(ushort);        // 25.6 MB
  ushort* Wt0     = (ushort*)ws;   ws += 128 * 128 * sizeof(ushort);
  ushort* Wt1     = (ushort*)ws;   ws += 128 * 128 * sizeof(ushort);
  int*    row_ptr = (int*)ws;

  rowptr_kernel<<<(N_USERS + 1 + 255) / 256, 256, 0, stream>>>(
      s_rows, row_ptr, N_USERS, n_edges);
  wconv_kernel<<<2, 256, 0, stream>>>(W0, W1, (uint*)Wt0, (uint*)Wt1);

  const ushort* Wtl[2] = {Wt0, Wt1};
  for (int l = 0; l < 2; ++l) {
    // Layer 0 reads the ORIGINAL input (d_out is zeroed by the harness before
    // launch — never read out[0] before writing it). gemm0 streams the copy
    // user_embeds -> out[0]; spmm0's residual also comes from user_embeds.
    const float* Xl = (l == 0) ? user_embeds : (out + l * layer);
    gemm_kernel<<<(N_USERS + 63) / 64, 256, 0, stream>>>(
        Xl, Wtl[l], xt, l == 0 ? out : nullptr);
    spmm_kernel<<<(N_USERS + 15) / 16, 256, 0, stream>>>(
        xt, Xl, row_ptr, s_cols, s_values, out + (l + 1) * layer);
  }
}